// Round 3
// baseline (2764.346 us; speedup 1.0000x reference)
//
#include <hip/hip_runtime.h>
#include <hip/hip_bf16.h>

#define DEV __device__ __forceinline__

DEV float lrelu_(float x){ return x > 0.f ? x : 0.01f * x; }
DEV float ssp_(float x){ float sp = fmaxf(x, 0.f) + log1pf(__expf(-fabsf(x))); return sp - 0.69314718055994530942f; }
DEV float sigm_(float x){ return 1.f / (1.f + __expf(-x)); }

// 4x4 register-tile FMA block: acc[i][j] += xa[i][kk] * wa[kk][j]
DEV void fma44(float (&acc)[4][4], const float4 (&xa)[4], const float4 (&wa)[4])
{
    #pragma unroll
    for (int kk = 0; kk < 4; kk++) {
        #pragma unroll
        for (int i = 0; i < 4; i++) {
            float x = ((const float*)&xa[i])[kk];
            #pragma unroll
            for (int j = 0; j < 4; j++)
                acc[i][j] += x * ((const float*)&wa[kk])[j];
        }
    }
}

// ================= generic tiled GEMM:  Y[N x 64] = act( (X .* scale?) @ W[K x 64] + b ) ==========
// 64 rows per block-iter, 256 threads, each thread 4 rows x 4 cols.
template<int K, int ACT, bool SCALE>
__global__ __launch_bounds__(256) void gemm64_kernel(const float* __restrict__ X,
                                                     const float* __restrict__ scale,
                                                     const float* __restrict__ W,
                                                     const float* __restrict__ B,
                                                     float* __restrict__ Y, int nrows)
{
    constexpr int XS = K + 4;            // padded LDS stride (keeps 16B align, breaks bank conflicts)
    constexpr int KQ = K / 4;
    __shared__ float Ws[K * 64];
    __shared__ float bs[64];
    __shared__ float Xs[64 * XS];
    for (int i = threadIdx.x; i < K * 64; i += 256) Ws[i] = W[i];
    if (threadIdx.x < 64) bs[threadIdx.x] = B[threadIdx.x];
    const int tr = threadIdx.x >> 4, tc = threadIdx.x & 15;
    const int r0 = tr * 4, c0 = tc * 4;
    for (int base = blockIdx.x * 64; base < nrows; base += gridDim.x * 64) {
        __syncthreads();
        for (int i = threadIdx.x; i < 64 * KQ; i += 256) {
            int row = i / KQ, kq = (i % KQ) * 4;
            int g = base + row;
            float4 v = make_float4(0.f, 0.f, 0.f, 0.f);
            if (g < nrows) {
                v = *(const float4*)&X[(size_t)g * K + kq];
                if (SCALE) { float s = scale[g]; v.x *= s; v.y *= s; v.z *= s; v.w *= s; }
            }
            *(float4*)&Xs[row * XS + kq] = v;
        }
        __syncthreads();
        float acc[4][4];
        #pragma unroll
        for (int i = 0; i < 4; i++)
            #pragma unroll
            for (int j = 0; j < 4; j++) acc[i][j] = bs[c0 + j];
        #pragma unroll
        for (int kq = 0; kq < K; kq += 4) {
            float4 xa[4], wa[4];
            #pragma unroll
            for (int i = 0; i < 4; i++) xa[i] = *(const float4*)&Xs[(r0 + i) * XS + kq];
            #pragma unroll
            for (int j = 0; j < 4; j++) wa[j] = *(const float4*)&Ws[(kq + j) * 64 + c0];
            fma44(acc, xa, wa);
        }
        #pragma unroll
        for (int i = 0; i < 4; i++) {
            int g = base + r0 + i;
            if (g < nrows) {
                float4 o;
                float* op = (float*)&o;
                #pragma unroll
                for (int j = 0; j < 4; j++) {
                    float a = acc[i][j];
                    if (ACT == 1) a = lrelu_(a);
                    else if (ACT == 2) a = fmaxf(a, 0.f);
                    else if (ACT == 3) a = ssp_(a);
                    op[j] = a;
                }
                *(float4*)&Y[(size_t)g * 64 + c0] = o;
            }
        }
    }
}

// ---------------- small scalar GEMV (pin encoder, C=16) ----------------
template<int K, int C, int ACT>
__global__ __launch_bounds__(256) void lin_kernel(const float* __restrict__ X,
                                                  const float* __restrict__ W,
                                                  const float* __restrict__ B,
                                                  float* __restrict__ Y, int nrows)
{
    constexpr int ROWS = 256 / C;
    __shared__ float Ws[K * C];
    __shared__ float bs[C];
    __shared__ float Xs[ROWS * K];
    for (int i = threadIdx.x; i < K * C; i += 256) Ws[i] = W[i];
    if (threadIdx.x < C) bs[threadIdx.x] = B[threadIdx.x];
    __syncthreads();
    const int r = threadIdx.x / C, c = threadIdx.x % C;
    for (int base = blockIdx.x * ROWS; base < nrows; base += gridDim.x * ROWS) {
        __syncthreads();
        for (int i = threadIdx.x; i < ROWS * K; i += 256) {
            int rr = base + i / K;
            Xs[i] = (rr < nrows) ? X[(size_t)rr * K + i % K] : 0.f;
        }
        __syncthreads();
        int row = base + r;
        if (row < nrows) {
            float acc = bs[c];
            #pragma unroll
            for (int k = 0; k < K; k++) acc += Xs[r * K + k] * Ws[k * C + c];
            if (ACT == 1) acc = lrelu_(acc);
            else if (ACT == 2) acc = fmaxf(acc, 0.f);
            Y[(size_t)row * C + c] = acc;
        }
    }
}

// ---------------- degrees ----------------
__global__ __launch_bounds__(256) void deg_kernel(const int* __restrict__ src, const int* __restrict__ dst,
                                                  int* __restrict__ degs, int* __restrict__ degd, int np)
{
    int p = blockIdx.x * 256 + threadIdx.x;
    if (p < np) { atomicAdd(&degs[src[p]], 1); atomicAdd(&degd[dst[p]], 1); }
}

__global__ __launch_bounds__(256) void norm_kernel(int* __restrict__ arr, int n)
{
    int i = blockIdx.x * 256 + threadIdx.x;
    if (i < n) {
        int v = arr[i]; if (v < 1) v = 1;
        arr[i] = __float_as_int(rsqrtf((float)v));
    }
}

// ---------------- edge weights for all 3 layers ----------------
__global__ __launch_bounds__(256) void edge_ew_kernel(const float* __restrict__ in_edge,
                                                      const float* __restrict__ elW, const float* __restrict__ elb,
                                                      const float* __restrict__ gW, const float* __restrict__ gb,
                                                      float* __restrict__ ew3, int ne)
{
    __shared__ float W[32], B[8], G[24], Gb[3];
    if (threadIdx.x < 32) W[threadIdx.x] = elW[threadIdx.x];
    if (threadIdx.x < 8)  B[threadIdx.x] = elb[threadIdx.x];
    if (threadIdx.x < 24) G[threadIdx.x] = gW[threadIdx.x];
    if (threadIdx.x < 3)  Gb[threadIdx.x] = gb[threadIdx.x];
    __syncthreads();
    for (int e = blockIdx.x * 256 + threadIdx.x; e < ne; e += gridDim.x * 256) {
        float x0 = in_edge[(size_t)e * 4 + 0], x1 = in_edge[(size_t)e * 4 + 1];
        float x2 = in_edge[(size_t)e * 4 + 2], x3 = in_edge[(size_t)e * 4 + 3];
        float ef[8];
        #pragma unroll
        for (int j = 0; j < 8; j++)
            ef[j] = lrelu_(B[j] + x0 * W[j] + x1 * W[8 + j] + x2 * W[16 + j] + x3 * W[24 + j]);
        #pragma unroll
        for (int i = 0; i < 3; i++) {
            float a = Gb[i];
            #pragma unroll
            for (int j = 0; j < 8; j++) a += ef[j] * G[i * 8 + j];
            ew3[(size_t)i * ne + e] = sigm_(a);
        }
    }
}

// ---------------- pins GraphConv scatter:  agg[dst] += node*srcnorm ----------------
__global__ __launch_bounds__(256) void pins_scatter(const float* __restrict__ nf, const float* __restrict__ snorm,
                                                    const int* __restrict__ src, const int* __restrict__ dst,
                                                    float* __restrict__ agg, int np)
{
    int idx = blockIdx.x * 256 + threadIdx.x;
    int p = idx >> 6; if (p >= np) return;
    int c = idx & 63;
    int s = src[p], d = dst[p];
    unsafeAtomicAdd(&agg[(size_t)d * 64 + c], nf[(size_t)s * 64 + c] * snorm[s]);
}

// ---------------- CFConv fused, register-tiled: 64 pins / block ----------------
__global__ __launch_bounds__(256) void cf_pin2_kernel(const float* __restrict__ pinf, const float* __restrict__ hv,
                                                      const int* __restrict__ psrc, const int* __restrict__ pdst,
                                                      const float* __restrict__ W1, const float* __restrict__ B1,
                                                      const float* __restrict__ W2, const float* __restrict__ B2,
                                                      float* __restrict__ h_cf, int np)
{
    __shared__ float Ws1[16 * 64], Ws2[64 * 64], bs1[64], bs2[64];
    __shared__ float PF[64 * 20], T1[64 * 68], HE[64 * 68];
    __shared__ int srcS[64], dstS[64];
    for (int i = threadIdx.x; i < 16 * 64; i += 256) Ws1[i] = W1[i];
    for (int i = threadIdx.x; i < 64 * 64; i += 256) Ws2[i] = W2[i];
    if (threadIdx.x < 64) { bs1[threadIdx.x] = B1[threadIdx.x]; bs2[threadIdx.x] = B2[threadIdx.x]; }
    const int tr = threadIdx.x >> 4, tc = threadIdx.x & 15;
    const int r0 = tr * 4, c0 = tc * 4;
    int base = blockIdx.x * 64;
    if (base >= np) return;
    {
        int row = threadIdx.x >> 2, kq = (threadIdx.x & 3) * 4;
        int p = base + row;
        float4 v = make_float4(0.f, 0.f, 0.f, 0.f);
        if (p < np) v = *(const float4*)&pinf[(size_t)p * 16 + kq];
        *(float4*)&PF[row * 20 + kq] = v;
        if (threadIdx.x < 64) {
            int pp = base + threadIdx.x;
            srcS[threadIdx.x] = (pp < np) ? psrc[pp] : 0;
            dstS[threadIdx.x] = (pp < np) ? pdst[pp] : 0;
        }
    }
    __syncthreads();
    // GEMM1: T1 = ssp(PF @ W1 + b1), K=16
    {
        float acc[4][4];
        #pragma unroll
        for (int i = 0; i < 4; i++)
            #pragma unroll
            for (int j = 0; j < 4; j++) acc[i][j] = bs1[c0 + j];
        #pragma unroll
        for (int kq = 0; kq < 16; kq += 4) {
            float4 xa[4], wa[4];
            #pragma unroll
            for (int i = 0; i < 4; i++) xa[i] = *(const float4*)&PF[(r0 + i) * 20 + kq];
            #pragma unroll
            for (int j = 0; j < 4; j++) wa[j] = *(const float4*)&Ws1[(kq + j) * 64 + c0];
            fma44(acc, xa, wa);
        }
        #pragma unroll
        for (int i = 0; i < 4; i++) {
            float4 o;
            float* op = (float*)&o;
            #pragma unroll
            for (int j = 0; j < 4; j++) op[j] = ssp_(acc[i][j]);
            *(float4*)&T1[(r0 + i) * 68 + c0] = o;
        }
    }
    __syncthreads();
    // GEMM2: HE = ssp(T1 @ W2 + b2), K=64
    {
        float acc[4][4];
        #pragma unroll
        for (int i = 0; i < 4; i++)
            #pragma unroll
            for (int j = 0; j < 4; j++) acc[i][j] = bs2[c0 + j];
        #pragma unroll
        for (int kq = 0; kq < 64; kq += 4) {
            float4 xa[4], wa[4];
            #pragma unroll
            for (int i = 0; i < 4; i++) xa[i] = *(const float4*)&T1[(r0 + i) * 68 + kq];
            #pragma unroll
            for (int j = 0; j < 4; j++) wa[j] = *(const float4*)&Ws2[(kq + j) * 64 + c0];
            fma44(acc, xa, wa);
        }
        #pragma unroll
        for (int i = 0; i < 4; i++) {
            float4 o;
            float* op = (float*)&o;
            #pragma unroll
            for (int j = 0; j < 4; j++) op[j] = ssp_(acc[i][j]);
            *(float4*)&HE[(r0 + i) * 68 + c0] = o;
        }
    }
    __syncthreads();
    // scatter: m = hv[pdst] * he -> atomicAdd h_cf[psrc]
    int lane = threadIdx.x & 63, wv = threadIdx.x >> 6;
    #pragma unroll 4
    for (int i = 0; i < 16; i++) {
        int pl = wv * 16 + i;
        int p = base + pl;
        if (p < np) {
            float m = hv[(size_t)dstS[pl] * 64 + lane] * HE[pl * 68 + lane];
            unsafeAtomicAdd(&h_cf[(size_t)srcS[pl] * 64 + lane], m);
        }
    }
}

// ---------------- SAGE edge scatter-max ----------------
__global__ __launch_bounds__(256) void sage_edge_kernel(const float* __restrict__ hp, const float* __restrict__ ew,
                                                        const int* __restrict__ esrc, const int* __restrict__ edst,
                                                        unsigned int* __restrict__ h_ng, int ne)
{
    long long idx = (long long)blockIdx.x * 256 + threadIdx.x;
    int e = (int)(idx >> 6); if (e >= ne) return;
    int c = (int)(idx & 63);
    int s = esrc[e], d = edst[e];
    float v = hp[(size_t)s * 64 + c] * ew[e];   // v >= 0 always
    atomicMax(&h_ng[(size_t)d * 64 + c], __float_as_uint(v));
}

// ---------------- combine (16 rows/block): lrelu(max(ssp(h_cf@Wc+bc), nf@Ws + h_ng@Wn + sb)) ------
__global__ __launch_bounds__(256) void combine2_kernel(const float* __restrict__ h_cf, const float* __restrict__ nf,
                                                       const float* __restrict__ h_ng,
                                                       const float* __restrict__ cW, const float* __restrict__ cB,
                                                       const float* __restrict__ sW, const float* __restrict__ nW,
                                                       const float* __restrict__ sB,
                                                       float* __restrict__ out, int n)
{
    __shared__ float Wc[64 * 64], Wsf[64 * 64], Wng[64 * 64];
    __shared__ float bc[64], bsg[64];
    __shared__ float Xc[16 * 68], Xf[16 * 68], Xn[16 * 68];
    for (int i = threadIdx.x; i < 64 * 64; i += 256) { Wc[i] = cW[i]; Wsf[i] = sW[i]; Wng[i] = nW[i]; }
    if (threadIdx.x < 64) { bc[threadIdx.x] = cB[threadIdx.x]; bsg[threadIdx.x] = sB[threadIdx.x]; }
    const int tr = threadIdx.x >> 4, tc = threadIdx.x & 15;
    const int c0 = tc * 4;
    int base = blockIdx.x * 16;
    if (base >= n) return;
    {
        int i = threadIdx.x;          // 16 rows x 16 qgroups = 256
        int row = i >> 4, kq = (i & 15) * 4;
        int g = base + row;
        float4 a = make_float4(0,0,0,0), b = a, c = a;
        if (g < n) {
            a = *(const float4*)&h_cf[(size_t)g * 64 + kq];
            b = *(const float4*)&nf[(size_t)g * 64 + kq];
            c = *(const float4*)&h_ng[(size_t)g * 64 + kq];
        }
        *(float4*)&Xc[row * 68 + kq] = a;
        *(float4*)&Xf[row * 68 + kq] = b;
        *(float4*)&Xn[row * 68 + kq] = c;
    }
    __syncthreads();
    float a1[4], a2[4];
    #pragma unroll
    for (int j = 0; j < 4; j++) { a1[j] = bc[c0 + j]; a2[j] = bsg[c0 + j]; }
    const int row = tr;
    #pragma unroll
    for (int kq = 0; kq < 64; kq += 4) {
        float4 xc = *(const float4*)&Xc[row * 68 + kq];
        float4 xf = *(const float4*)&Xf[row * 68 + kq];
        float4 xn = *(const float4*)&Xn[row * 68 + kq];
        #pragma unroll
        for (int kk = 0; kk < 4; kk++) {
            float4 wc = *(const float4*)&Wc[(kq + kk) * 64 + c0];
            float4 wsf = *(const float4*)&Wsf[(kq + kk) * 64 + c0];
            float4 wng = *(const float4*)&Wng[(kq + kk) * 64 + c0];
            float x1 = ((const float*)&xc)[kk], x2 = ((const float*)&xf)[kk], x3 = ((const float*)&xn)[kk];
            #pragma unroll
            for (int j = 0; j < 4; j++) {
                a1[j] += x1 * ((const float*)&wc)[j];
                a2[j] += x2 * ((const float*)&wsf)[j] + x3 * ((const float*)&wng)[j];
            }
        }
    }
    int g = base + row;
    if (g < n) {
        float4 o;
        float* op = (float*)&o;
        #pragma unroll
        for (int j = 0; j < 4; j++) op[j] = lrelu_(fmaxf(ssp_(a1[j]), a2[j]));
        *(float4*)&out[(size_t)g * 64 + c0] = o;
    }
}

// ---------------- node head (32 rows/block, 3-stage MLP) ----------------
__global__ __launch_bounds__(256) void node_head2_kernel(const float* __restrict__ in_node, const float* __restrict__ nf,
                                                         const float* __restrict__ W1, const float* __restrict__ B1,
                                                         const float* __restrict__ W2, const float* __restrict__ B2,
                                                         const float* __restrict__ W3, const float* __restrict__ B3,
                                                         float* __restrict__ out, int n)
{
    __shared__ float Ws1[80 * 64], Ws2[64 * 64], Ws3[64 * 4];
    __shared__ float bs1[64], bs2[64], bs3[4];
    __shared__ float Xs[32 * 84];       // also reused as H2 (stride 68)
    __shared__ float H1[32 * 68];
    for (int i = threadIdx.x; i < 80 * 64; i += 256) Ws1[i] = W1[i];
    for (int i = threadIdx.x; i < 64 * 64; i += 256) Ws2[i] = W2[i];
    for (int i = threadIdx.x; i < 64 * 4; i += 256) Ws3[i] = W3[i];
    if (threadIdx.x < 64) { bs1[threadIdx.x] = B1[threadIdx.x]; bs2[threadIdx.x] = B2[threadIdx.x]; }
    if (threadIdx.x < 4) bs3[threadIdx.x] = B3[threadIdx.x];
    const int tr = threadIdx.x >> 4, tc = threadIdx.x & 15;
    const int r0 = tr * 2, c0 = tc * 4;
    int base = blockIdx.x * 32;
    if (base >= n) return;
    for (int i = threadIdx.x; i < 32 * 4; i += 256) {
        int row = i >> 2, kq = (i & 3) * 4;
        int g = base + row;
        float4 v = make_float4(0,0,0,0);
        if (g < n) v = *(const float4*)&in_node[(size_t)g * 16 + kq];
        *(float4*)&Xs[row * 84 + kq] = v;
    }
    for (int i = threadIdx.x; i < 32 * 16; i += 256) {
        int row = i >> 4, kq = (i & 15) * 4;
        int g = base + row;
        float4 v = make_float4(0,0,0,0);
        if (g < n) v = *(const float4*)&nf[(size_t)g * 64 + kq];
        *(float4*)&Xs[row * 84 + 16 + kq] = v;
    }
    __syncthreads();
    // GEMM1: K=80 -> H1 (lrelu)
    {
        float acc[2][4];
        #pragma unroll
        for (int i = 0; i < 2; i++)
            #pragma unroll
            for (int j = 0; j < 4; j++) acc[i][j] = bs1[c0 + j];
        #pragma unroll
        for (int kq = 0; kq < 80; kq += 4) {
            float4 xa[2], wa[4];
            #pragma unroll
            for (int i = 0; i < 2; i++) xa[i] = *(const float4*)&Xs[(r0 + i) * 84 + kq];
            #pragma unroll
            for (int j = 0; j < 4; j++) wa[j] = *(const float4*)&Ws1[(kq + j) * 64 + c0];
            #pragma unroll
            for (int kk = 0; kk < 4; kk++)
                #pragma unroll
                for (int i = 0; i < 2; i++) {
                    float x = ((const float*)&xa[i])[kk];
                    #pragma unroll
                    for (int j = 0; j < 4; j++) acc[i][j] += x * ((const float*)&wa[kk])[j];
                }
        }
        #pragma unroll
        for (int i = 0; i < 2; i++) {
            float4 o; float* op = (float*)&o;
            #pragma unroll
            for (int j = 0; j < 4; j++) op[j] = lrelu_(acc[i][j]);
            *(float4*)&H1[(r0 + i) * 68 + c0] = o;
        }
    }
    __syncthreads();
    // GEMM2: K=64 -> H2 (= Xs region, stride 68) (lrelu)
    float* H2 = Xs;
    {
        float acc[2][4];
        #pragma unroll
        for (int i = 0; i < 2; i++)
            #pragma unroll
            for (int j = 0; j < 4; j++) acc[i][j] = bs2[c0 + j];
        #pragma unroll
        for (int kq = 0; kq < 64; kq += 4) {
            float4 xa[2], wa[4];
            #pragma unroll
            for (int i = 0; i < 2; i++) xa[i] = *(const float4*)&H1[(r0 + i) * 68 + kq];
            #pragma unroll
            for (int j = 0; j < 4; j++) wa[j] = *(const float4*)&Ws2[(kq + j) * 64 + c0];
            #pragma unroll
            for (int kk = 0; kk < 4; kk++)
                #pragma unroll
                for (int i = 0; i < 2; i++) {
                    float x = ((const float*)&xa[i])[kk];
                    #pragma unroll
                    for (int j = 0; j < 4; j++) acc[i][j] += x * ((const float*)&wa[kk])[j];
                }
        }
        __syncthreads();   // Xs no longer needed; safe to overwrite as H2
        #pragma unroll
        for (int i = 0; i < 2; i++) {
            float4 o; float* op = (float*)&o;
            #pragma unroll
            for (int j = 0; j < 4; j++) op[j] = lrelu_(acc[i][j]);
            *(float4*)&H2[(r0 + i) * 68 + c0] = o;
        }
    }
    __syncthreads();
    // GEMM3: K=64, C=4 -> sigmoid
    if (threadIdx.x < 128) {
        int row = threadIdx.x >> 2, c = threadIdx.x & 3;
        float acc = bs3[c];
        #pragma unroll
        for (int kq = 0; kq < 64; kq += 4) {
            float4 h = *(const float4*)&H2[row * 68 + kq];
            #pragma unroll
            for (int j = 0; j < 4; j++) acc += ((const float*)&h)[j] * Ws3[(kq + j) * 4 + c];
        }
        int g = base + row;
        if (g < n) out[(size_t)g * 4 + c] = sigm_(acc);
    }
}

// ---------------- net head (32 rows/block, 3-stage MLP, C_out=1) ----------------
__global__ __launch_bounds__(256) void net_head2_kernel(const float* __restrict__ in_net, const float* __restrict__ tf,
                                                        const float* __restrict__ W1, const float* __restrict__ B1,
                                                        const float* __restrict__ W2, const float* __restrict__ B2,
                                                        const float* __restrict__ W3, const float* __restrict__ B3,
                                                        float* __restrict__ out, int n)
{
    __shared__ float Ws1[72 * 64], Ws2[64 * 64], Ws3[64];
    __shared__ float bs1[64], bs2[64], bs3[1];
    __shared__ float Xs[32 * 76];       // reused as H2 (stride 68)
    __shared__ float H1[32 * 68];
    for (int i = threadIdx.x; i < 72 * 64; i += 256) Ws1[i] = W1[i];
    for (int i = threadIdx.x; i < 64 * 64; i += 256) Ws2[i] = W2[i];
    if (threadIdx.x < 64) { Ws3[threadIdx.x] = W3[threadIdx.x]; bs1[threadIdx.x] = B1[threadIdx.x]; bs2[threadIdx.x] = B2[threadIdx.x]; }
    if (threadIdx.x == 0) bs3[0] = B3[0];
    const int tr = threadIdx.x >> 4, tc = threadIdx.x & 15;
    const int r0 = tr * 2, c0 = tc * 4;
    int base = blockIdx.x * 32;
    if (base >= n) return;
    for (int i = threadIdx.x; i < 32 * 2; i += 256) {
        int row = i >> 1, kq = (i & 1) * 4;
        int g = base + row;
        float4 v = make_float4(0,0,0,0);
        if (g < n) v = *(const float4*)&in_net[(size_t)g * 8 + kq];
        *(float4*)&Xs[row * 76 + kq] = v;
    }
    for (int i = threadIdx.x; i < 32 * 16; i += 256) {
        int row = i >> 4, kq = (i & 15) * 4;
        int g = base + row;
        float4 v = make_float4(0,0,0,0);
        if (g < n) v = *(const float4*)&tf[(size_t)g * 64 + kq];
        *(float4*)&Xs[row * 76 + 8 + kq] = v;
    }
    __syncthreads();
    {
        float acc[2][4];
        #pragma unroll
        for (int i = 0; i < 2; i++)
            #pragma unroll
            for (int j = 0; j < 4; j++) acc[i][j] = bs1[c0 + j];
        #pragma unroll
        for (int kq = 0; kq < 72; kq += 4) {
            float4 xa[2], wa[4];
            #pragma unroll
            for (int i = 0; i < 2; i++) xa[i] = *(const float4*)&Xs[(r0 + i) * 76 + kq];
            #pragma unroll
            for (int j = 0; j < 4; j++) wa[j] = *(const float4*)&Ws1[(kq + j) * 64 + c0];
            #pragma unroll
            for (int kk = 0; kk < 4; kk++)
                #pragma unroll
                for (int i = 0; i < 2; i++) {
                    float x = ((const float*)&xa[i])[kk];
                    #pragma unroll
                    for (int j = 0; j < 4; j++) acc[i][j] += x * ((const float*)&wa[kk])[j];
                }
        }
        #pragma unroll
        for (int i = 0; i < 2; i++) {
            float4 o; float* op = (float*)&o;
            #pragma unroll
            for (int j = 0; j < 4; j++) op[j] = lrelu_(acc[i][j]);
            *(float4*)&H1[(r0 + i) * 68 + c0] = o;
        }
    }
    __syncthreads();
    float* H2 = Xs;
    {
        float acc[2][4];
        #pragma unroll
        for (int i = 0; i < 2; i++)
            #pragma unroll
            for (int j = 0; j < 4; j++) acc[i][j] = bs2[c0 + j];
        #pragma unroll
        for (int kq = 0; kq < 64; kq += 4) {
            float4 xa[2], wa[4];
            #pragma unroll
            for (int i = 0; i < 2; i++) xa[i] = *(const float4*)&H1[(r0 + i) * 68 + kq];
            #pragma unroll
            for (int j = 0; j < 4; j++) wa[j] = *(const float4*)&Ws2[(kq + j) * 64 + c0];
            #pragma unroll
            for (int kk = 0; kk < 4; kk++)
                #pragma unroll
                for (int i = 0; i < 2; i++) {
                    float x = ((const float*)&xa[i])[kk];
                    #pragma unroll
                    for (int j = 0; j < 4; j++) acc[i][j] += x * ((const float*)&wa[kk])[j];
                }
        }
        __syncthreads();
        #pragma unroll
        for (int i = 0; i < 2; i++) {
            float4 o; float* op = (float*)&o;
            #pragma unroll
            for (int j = 0; j < 4; j++) op[j] = lrelu_(acc[i][j]);
            *(float4*)&H2[(r0 + i) * 68 + c0] = o;
        }
    }
    __syncthreads();
    if (threadIdx.x < 32) {
        int row = threadIdx.x;
        float acc = bs3[0];
        #pragma unroll
        for (int kq = 0; kq < 64; kq += 4) {
            float4 h = *(const float4*)&H2[row * 68 + kq];
            float4 w = *(const float4*)&Ws3[kq];
            acc += h.x * w.x + h.y * w.y + h.z * w.z + h.w * w.w;
        }
        int g = base + row;
        if (g < n) out[g] = sigm_(acc);
    }
}

extern "C" void kernel_launch(void* const* d_in, const int* in_sizes, int n_in,
                              void* d_out, int out_size, void* d_ws, size_t ws_size,
                              hipStream_t stream)
{
    (void)in_sizes; (void)n_in; (void)out_size; (void)ws_size;
    constexpr int Nn = 100000, Nt = 30000, Np = 400000, Ne = 1000000;
    constexpr int H = 64, L = 3, T = 4;

    auto fpt = [&](int i){ return (const float*)d_in[i]; };
    auto ipt = [&](int i){ return (const int*)d_in[i]; };

    const float* in_node = fpt(0);
    const float* in_net  = fpt(1);
    const float* in_pin  = fpt(2);
    const float* in_edge = fpt(3);
    const int* psrc = ipt(4);
    const int* pdst = ipt(5);
    const int* esrc = ipt(6);
    const int* edst = ipt(7);

    float* ws = (float*)d_ws;
    size_t o = 0;
    auto alloc = [&](size_t nel){ float* p = ws + o; o += nel; return p; };
    float* node_a = alloc((size_t)Nn * H);
    float* node_b = alloc((size_t)Nn * H);
    float* net_a  = alloc((size_t)Nt * H);
    float* net_b  = alloc((size_t)Nt * H);
    float* agg    = alloc((size_t)Nt * H);
    float* hv     = alloc((size_t)Nt * H);
    float* pinf   = alloc((size_t)Np * 16);
    float* h_cf   = alloc((size_t)Nn * H);
    float* hp     = alloc((size_t)Nn * H);
    float* h_ng   = alloc((size_t)Nn * H);
    float* ew3    = alloc((size_t)3 * Ne);
    float* snorm  = alloc((size_t)Nn);
    float* dnorm  = alloc((size_t)Nt);

    // degree norms
    hipMemsetAsync(snorm, 0, (size_t)Nn * 4, stream);
    hipMemsetAsync(dnorm, 0, (size_t)Nt * 4, stream);
    deg_kernel<<<(Np + 255) / 256, 256, 0, stream>>>(psrc, pdst, (int*)snorm, (int*)dnorm, Np);
    norm_kernel<<<(Nn + 255) / 256, 256, 0, stream>>>((int*)snorm, Nn);
    norm_kernel<<<(Nt + 255) / 256, 256, 0, stream>>>((int*)dnorm, Nt);

    const int gNn = (Nn + 63) / 64, gNt = (Nt + 63) / 64;

    // input encoders
    gemm64_kernel<16, 1, false><<<gNn, 256, 0, stream>>>(in_node, nullptr, fpt(8),  fpt(9),  node_a, Nn);
    gemm64_kernel< 8, 1, false><<<gNt, 256, 0, stream>>>(in_net,  nullptr, fpt(10), fpt(11), net_a,  Nt);
    lin_kernel<8, 16, 1><<<2048, 256, 0, stream>>>(in_pin, fpt(12), fpt(13), pinf, Np);
    edge_ew_kernel<<<2048, 256, 0, stream>>>(in_edge, fpt(14), fpt(15), fpt(16), fpt(17), ew3, Ne);

    float* ncur = node_a; float* nnew = node_b;
    float* tcur = net_a;  float* tnew = net_b;

    for (int i = 0; i < L; i++) {
        // pins GraphConv (node -> net)
        hipMemsetAsync(agg, 0, (size_t)Nt * H * 4, stream);
        pins_scatter<<<(Np * 64 + 255) / 256, 256, 0, stream>>>(ncur, snorm, psrc, pdst, agg, Np);
        gemm64_kernel<64, 1, true><<<gNt, 256, 0, stream>>>(agg, dnorm, fpt(18) + (size_t)i * 4096, fpt(19) + (size_t)i * 64, tnew, Nt);

        // CFConv (net -> node)
        gemm64_kernel<64, 0, false><<<gNt, 256, 0, stream>>>(tcur, nullptr, fpt(20) + (size_t)i * 4096, fpt(21) + (size_t)i * 64, hv, Nt);
        hipMemsetAsync(h_cf, 0, (size_t)Nn * H * 4, stream);
        cf_pin2_kernel<<<(Np + 63) / 64, 256, 0, stream>>>(pinf, hv, psrc, pdst,
                                                           fpt(22) + (size_t)i * 1024, fpt(23) + (size_t)i * 64,
                                                           fpt(24) + (size_t)i * 4096, fpt(25) + (size_t)i * 64,
                                                           h_cf, Np);

        // SAGE (near)
        gemm64_kernel<64, 2, false><<<gNn, 256, 0, stream>>>(ncur, nullptr, fpt(28) + (size_t)i * 4096, fpt(29) + (size_t)i * 64, hp, Nn);
        hipMemsetAsync(h_ng, 0, (size_t)Nn * H * 4, stream);
        sage_edge_kernel<<<(int)(((long long)Ne * 64 + 255) / 256), 256, 0, stream>>>(hp, ew3 + (size_t)i * Ne, esrc, edst, (unsigned int*)h_ng, Ne);

        // combine + activations
        combine2_kernel<<<(Nn + 15) / 16, 256, 0, stream>>>(h_cf, ncur, h_ng,
                                                            fpt(26) + (size_t)i * 4096, fpt(27) + (size_t)i * 64,
                                                            fpt(30) + (size_t)i * 4096, fpt(31) + (size_t)i * 4096,
                                                            fpt(32) + (size_t)i * 64,
                                                            nnew, Nn);
        float* t;
        t = ncur; ncur = nnew; nnew = t;
        t = tcur; tcur = tnew; tnew = t;
    }

    float* out = (float*)d_out;
    node_head2_kernel<<<(Nn + 31) / 32, 256, 0, stream>>>(in_node, ncur, fpt(33), fpt(34), fpt(35), fpt(36), fpt(37), fpt(38), out, Nn);
    net_head2_kernel<<<(Nt + 31) / 32, 256, 0, stream>>>(in_net, tcur, fpt(39), fpt(40), fpt(41), fpt(42), fpt(43), fpt(44), out + (size_t)Nn * T, Nt);
}